// Round 2
// baseline (194.811 us; speedup 1.0000x reference)
//
#include <hip/hip_runtime.h>
#include <hip/hip_bf16.h>
#include <math.h>

// NonLocalEncoder 'sharing': M=N=768, C=256, IMG=1024, CAT=1792
#define MM 768
#define CC 256
#define EPSV 1e-4f

__device__ __forceinline__ float sigmoidf_(float x) { return 1.0f / (1.0f + expf(-x)); }

// ===========================================================================
// Kernel A (grid 1928 x 256): fused independent preprocessing
//   blocks [0,1536)   : conflict max-pool (768 edge rows, 768 loop rows)
//   blocks [1536,1920): pred0 heads, 4 rows/block (1536 rows) -> out[0:1536)
//   blocks [1920,1928): img-bias partials (image slab of W collapses to a
//                       constant [256] vector per head; 4 k-chunks x 2 heads)
// ===========================================================================
__global__ __launch_bounds__(256) void k_prep(
    const float* __restrict__ edge_x, const float* __restrict__ loop_x,
    const float* __restrict__ image_x,
    const float* __restrict__ ecm, const float* __restrict__ lcm,
    const float* __restrict__ We3, const float* __restrict__ Wl3,
    const float* __restrict__ Wep1, const float* __restrict__ bep1,
    const float* __restrict__ Wep2, const float* __restrict__ bep2,
    const float* __restrict__ Wlp1, const float* __restrict__ blp1,
    const float* __restrict__ Wlp2, const float* __restrict__ blp2,
    float* __restrict__ out, float* __restrict__ efc, float* __restrict__ lfc,
    float* __restrict__ imgpart)
{
    int bid = blockIdx.x;
    int t   = threadIdx.x;

    if (bid < 1536) {
        // ---- conflict-masked max pool: out[m,c] = max_j mask[m,j]*x[j,c] ----
        __shared__ int   s_cnt;
        __shared__ int   s_idx[MM];
        __shared__ float s_val[MM];
        bool isLoop = bid >= MM;
        int  m      = bid & (MM - 1);
        const float* mask = isLoop ? lcm : ecm;
        const float* x    = isLoop ? loop_x : edge_x;
        float*       o    = isLoop ? lfc : efc;

        if (t == 0) s_cnt = 0;
        __syncthreads();
        #pragma unroll
        for (int r = 0; r < 3; ++r) {
            int j = t + r * 256;
            float v = mask[m * MM + j];
            if (v != 0.0f) {
                int p = atomicAdd(&s_cnt, 1);
                s_idx[p] = j;
                s_val[p] = v;
            }
        }
        __syncthreads();
        int cnt = s_cnt;
        float acc = (cnt < MM) ? 0.0f : -INFINITY;  // zero-entries contribute 0
        #pragma unroll 4
        for (int i = 0; i < cnt; ++i)
            acc = fmaxf(acc, s_val[i] * x[s_idx[i] * CC + t]);
        o[m * CC + t] = acc;

    } else if (bid < 1920) {
        // ---- pred0: one wave per row ----
        int wave = t >> 6, lane = t & 63;
        int row  = (bid - 1536) * 4 + wave;          // 0..1535
        const float *x, *W1, *b1, *W2;
        float b2v;
        if (row < MM) { x = edge_x + row * CC;        W1 = Wep1; b1 = bep1; W2 = Wep2; b2v = bep2[0]; }
        else          { x = loop_x + (row - MM) * CC; W1 = Wlp1; b1 = blp1; W2 = Wlp2; b2v = blp2[0]; }

        float a0 = 0.f, a1 = 0.f, a2 = 0.f, a3 = 0.f;
        for (int cc = 0; cc < CC; cc += 4) {
            float4 xv = *reinterpret_cast<const float4*>(x + cc);
            a0 = fmaf(xv.x, W1[(cc + 0) * 64 + lane], a0);
            a1 = fmaf(xv.y, W1[(cc + 1) * 64 + lane], a1);
            a2 = fmaf(xv.z, W1[(cc + 2) * 64 + lane], a2);
            a3 = fmaf(xv.w, W1[(cc + 3) * 64 + lane], a3);
        }
        float h = fmaxf(b1[lane] + ((a0 + a1) + (a2 + a3)), 0.0f);
        float p = h * W2[lane];
        #pragma unroll
        for (int off = 32; off; off >>= 1) p += __shfl_xor(p, off, 64);
        if (lane == 0) out[row] = sigmoidf_(p + b2v);

    } else {
        // ---- img bias partials ----
        int sub   = bid - 1920;       // 0..7
        int chunk = sub & 3;
        int head  = sub >> 2;
        const float* W = head ? Wl3 : We3;
        int k0 = chunk * 256;
        float s = 0.0f;
        #pragma unroll 4
        for (int k = 0; k < 256; ++k)
            s = fmaf(image_x[k0 + k], W[(768 + k0 + k) * CC + t], s);
        imgpart[head * 1024 + chunk * 256 + t] = s;
    }
}

// ===========================================================================
// Kernel B (grid 192 x 512): weighted broadcast sums, both directions.
//   blocks [0,96)  : efl[m,c] = (sum_n w[n,m]*loop_x[n,c]) / max(colsum,eps)
//   blocks [96,192): lfe[n,c] = (sum_m w[n,m]*edge_x[m,c]) / max(rowsum,eps)
// Each block owns 8 output rows. Phase 1 computes its w-slice ONCE into LDS
// (wv[768][8]); phase 1.5 reduces the 8 sums; phase 2 splits the 768-long
// summation across the two 256-thread halves (c = t&255), combining via LDS.
// ===========================================================================
__global__ __launch_bounds__(512) void k_bsum(
    const float* __restrict__ lem, const float* __restrict__ edge_x,
    const float* __restrict__ loop_x, const float* __restrict__ pred,
    float* __restrict__ efl, float* __restrict__ lfe)
{
    __shared__ float4 s_wv4[1536];   // 24KB: wv[s][i], s=summation idx, i=row-in-block
    __shared__ float  s_ps[512];     // 2KB partial sums [64][8]
    __shared__ float  s_sum[8];
    float* s_wv = reinterpret_cast<float*>(s_wv4);

    int bid = blockIdx.x;
    int t   = threadIdx.x;
    const float* e0 = pred;
    const float* l0 = pred + MM;

    bool isE = bid < 96;
    int  r0  = (isE ? bid : bid - 96) * 8;
    const float* ownp = isE ? e0 : l0;  // pred of the 8 owned rows
    const float* othp = isE ? l0 : e0;  // pred along summation axis

    float own[8];
    #pragma unroll
    for (int i = 0; i < 8; ++i) own[i] = ownp[r0 + i];

    // phase 1: wv[s*8+i] = lem * |oth[s] - own[i]|
    #pragma unroll
    for (int k = 0; k < 12; ++k) {
        int idx = t + k * 512;
        int s = idx >> 3, i = idx & 7;
        float lm = isE ? lem[s * MM + r0 + i] : lem[(r0 + i) * MM + s];
        s_wv[idx] = lm * fabsf(othp[s] - own[i]);
    }
    __syncthreads();

    // phase 1.5: sums over s for the 8 rows
    {
        int g = t >> 3, i = t & 7;
        float s = 0.f;
        #pragma unroll
        for (int j = 0; j < 12; ++j) s += s_wv[(g + 64 * j) * 8 + i];
        s_ps[g * 8 + i] = s;
    }
    __syncthreads();
    if (t < 8) {
        float s = 0.f;
        for (int g = 0; g < 64; ++g) s += s_ps[g * 8 + t];
        s_sum[t] = fmaxf(s, EPSV);
    }

    // phase 2: half h accumulates s in [h*384, h*384+384)
    const float* xsrc = isE ? loop_x : edge_x;
    int c = t & 255, h = t >> 8;
    float acc[8] = {0.f, 0.f, 0.f, 0.f, 0.f, 0.f, 0.f, 0.f};
    int s0 = h * 384;
    #pragma unroll 2
    for (int s = s0; s < s0 + 384; ++s) {
        float4 w0 = *reinterpret_cast<const float4*>(&s_wv[s * 8]);
        float4 w1 = *reinterpret_cast<const float4*>(&s_wv[s * 8 + 4]);
        float xv = xsrc[s * CC + c];
        acc[0] = fmaf(w0.x, xv, acc[0]);
        acc[1] = fmaf(w0.y, xv, acc[1]);
        acc[2] = fmaf(w0.z, xv, acc[2]);
        acc[3] = fmaf(w0.w, xv, acc[3]);
        acc[4] = fmaf(w1.x, xv, acc[4]);
        acc[5] = fmaf(w1.y, xv, acc[5]);
        acc[6] = fmaf(w1.z, xv, acc[6]);
        acc[7] = fmaf(w1.w, xv, acc[7]);
    }
    __syncthreads();              // all done reading s_wv; s_sum visible
    if (h == 1) {
        #pragma unroll
        for (int i = 0; i < 8; ++i) s_wv[i * CC + c] = acc[i];
    }
    __syncthreads();
    if (h == 0) {
        float* outp = isE ? efl : lfe;
        #pragma unroll
        for (int i = 0; i < 8; ++i)
            outp[(r0 + i) * CC + c] = (acc[i] + s_wv[i * CC + c]) / s_sum[i];
    }
}

// ===========================================================================
// Kernel C (grid (96,2) x 512): x2 = relu(cat @ W + b) fused with pred1.
// 8 output rows per block; k (=768 non-image concat rows) split across the
// two thread-halves; activations combined in an 8KB LDS tile; each of the 8
// waves then runs the pred head for one row. ex2/lx2 never hit global memory.
// ===========================================================================
__global__ __launch_bounds__(512) void k_cat(
    const float* __restrict__ edge_x, const float* __restrict__ loop_x,
    const float* __restrict__ efl, const float* __restrict__ lfe,
    const float* __restrict__ efc, const float* __restrict__ lfc,
    const float* __restrict__ We3, const float* __restrict__ be3,
    const float* __restrict__ Wl3, const float* __restrict__ bl3,
    const float* __restrict__ imgpart,
    const float* __restrict__ Wep1, const float* __restrict__ bep1,
    const float* __restrict__ Wep2, const float* __restrict__ bep2,
    const float* __restrict__ Wlp1, const float* __restrict__ blp1,
    const float* __restrict__ Wlp2, const float* __restrict__ blp2,
    float* __restrict__ out)
{
    __shared__ float4 s_act4[8 * 64];   // 8KB: act[8][256]
    float* s_act = reinterpret_cast<float*>(s_act4);

    int head = blockIdx.y;
    const float* W  = head ? Wl3 : We3;
    const float* b  = head ? bl3 : be3;
    const float* x0 = head ? loop_x : edge_x;
    const float* x1 = head ? lfe : efl;
    const float* x2 = head ? lfc : efc;
    const float* ip = imgpart + head * 1024;

    int m0 = blockIdx.x * 8;
    int t  = threadIdx.x;
    int c  = t & 255, h = t >> 8;

    float acc[8] = {0.f, 0.f, 0.f, 0.f, 0.f, 0.f, 0.f, 0.f};

    auto accum = [&](const float* src, int ks, int kw, int len) {
        for (int kk = 0; kk < len; kk += 4) {
            float4 xv[8];
            #pragma unroll
            for (int i = 0; i < 8; ++i)
                xv[i] = *reinterpret_cast<const float4*>(src + (m0 + i) * CC + ks + kk);
            #pragma unroll
            for (int j = 0; j < 4; ++j) {
                float wv = W[(kw + kk + j) * CC + c];
                #pragma unroll
                for (int i = 0; i < 8; ++i)
                    acc[i] = fmaf(reinterpret_cast<const float*>(&xv[i])[j], wv, acc[i]);
            }
        }
    };
    // concat rows: [0,256)=x, [256,512)=x_from_other, [512,768)=x_from_conflict
    if (h == 0) { accum(x0, 0, 0, 256);   accum(x1, 0, 256, 128); }
    else        { accum(x1, 128, 384, 128); accum(x2, 0, 512, 256); }

    if (h == 1) {
        #pragma unroll
        for (int i = 0; i < 8; ++i) s_act[i * CC + c] = acc[i];
    }
    __syncthreads();
    if (h == 0) {
        float bias = b[c] + ip[c] + ip[256 + c] + ip[512 + c] + ip[768 + c];
        #pragma unroll
        for (int i = 0; i < 8; ++i)
            s_act[i * CC + c] = fmaxf(bias + acc[i] + s_act[i * CC + c], 0.0f);
    }
    __syncthreads();

    // fused pred head: wave w handles row m0+w
    int wave = t >> 6, lane = t & 63;
    const float* W1 = head ? Wlp1 : Wep1;
    const float* b1 = head ? blp1 : bep1;
    const float* W2 = head ? Wlp2 : Wep2;
    float b2v       = head ? blp2[0] : bep2[0];
    const float* xr = s_act + wave * CC;

    float a0 = 0.f, a1 = 0.f, a2 = 0.f, a3 = 0.f;
    for (int cc = 0; cc < CC; cc += 4) {
        float4 xv = *reinterpret_cast<const float4*>(xr + cc);
        a0 = fmaf(xv.x, W1[(cc + 0) * 64 + lane], a0);
        a1 = fmaf(xv.y, W1[(cc + 1) * 64 + lane], a1);
        a2 = fmaf(xv.z, W1[(cc + 2) * 64 + lane], a2);
        a3 = fmaf(xv.w, W1[(cc + 3) * 64 + lane], a3);
    }
    float hh = fmaxf(b1[lane] + ((a0 + a1) + (a2 + a3)), 0.0f);
    float p = hh * W2[lane];
    #pragma unroll
    for (int off = 32; off; off >>= 1) p += __shfl_xor(p, off, 64);
    if (lane == 0) out[1536 + head * MM + m0 + wave] = sigmoidf_(p + b2v);
}

// ===========================================================================
extern "C" void kernel_launch(void* const* d_in, const int* in_sizes, int n_in,
                              void* d_out, int out_size, void* d_ws, size_t ws_size,
                              hipStream_t stream)
{
    const float* edge_x  = (const float*)d_in[0];
    const float* loop_x  = (const float*)d_in[1];
    const float* image_x = (const float*)d_in[2];
    const float* lem     = (const float*)d_in[3];
    const float* ecm     = (const float*)d_in[4];
    const float* lcm     = (const float*)d_in[5];
    // d_in[6..8] unused
    const float* We3  = (const float*)d_in[9];
    const float* be3  = (const float*)d_in[10];
    const float* Wl3  = (const float*)d_in[11];
    const float* bl3  = (const float*)d_in[12];
    const float* Wep1 = (const float*)d_in[13];
    const float* bep1 = (const float*)d_in[14];
    const float* Wep2 = (const float*)d_in[15];
    const float* bep2 = (const float*)d_in[16];
    const float* Wlp1 = (const float*)d_in[17];
    const float* blp1 = (const float*)d_in[18];
    const float* Wlp2 = (const float*)d_in[19];
    const float* blp2 = (const float*)d_in[20];

    float* out = (float*)d_out;          // [3072] = e0 | l0 | e1 | l1
    float* ws  = (float*)d_ws;

    // workspace (floats): imgpart 2048 | efl | lfe | efc | lfc  (~3.15 MB)
    float* imgpart = ws;
    float* efl     = ws + 2048;
    float* lfe     = efl + MM * CC;
    float* efc     = lfe + MM * CC;
    float* lfc     = efc + MM * CC;

    // A: conflict pools + pred0 + img-bias (independent)
    k_prep<<<1928, 256, 0, stream>>>(edge_x, loop_x, image_x, ecm, lcm,
                                     We3, Wl3,
                                     Wep1, bep1, Wep2, bep2,
                                     Wlp1, blp1, Wlp2, blp2,
                                     out, efc, lfc, imgpart);

    // B: both weighted broadcast sums (reads e0/l0 from out)
    k_bsum<<<192, 512, 0, stream>>>(lem, edge_x, loop_x, out, efl, lfe);

    // C: concat-GEMM + relu + fused pred1
    k_cat<<<dim3(96, 2), 512, 0, stream>>>(edge_x, loop_x, efl, lfe, efc, lfc,
                                           We3, be3, Wl3, bl3, imgpart,
                                           Wep1, bep1, Wep2, bep2,
                                           Wlp1, blp1, Wlp2, blp2, out);
}

// Round 3
// 169.858 us; speedup vs baseline: 1.1469x; 1.1469x over previous
//
#include <hip/hip_runtime.h>
#include <hip/hip_bf16.h>
#include <math.h>

// NonLocalEncoder 'sharing': M=N=768, C=256, IMG=1024, CAT=1792
#define MM 768
#define CC 256
#define EPSV 1e-4f

__device__ __forceinline__ float sigmoidf_(float x) { return 1.0f / (1.0f + expf(-x)); }

// ===========================================================================
// Kernel A (grid 1928 x 256): fused independent preprocessing
//   blocks [0,1536)   : conflict max-pool (ballot compaction + 4-acc gather)
//   blocks [1536,1920): pred0 heads, 4 rows/block -> out[0:1536)
//   blocks [1920,1928): img-bias partials (image slab of W -> constant [256])
// ===========================================================================
__global__ __launch_bounds__(256) void k_prep(
    const float* __restrict__ edge_x, const float* __restrict__ loop_x,
    const float* __restrict__ image_x,
    const float* __restrict__ ecm, const float* __restrict__ lcm,
    const float* __restrict__ We3, const float* __restrict__ Wl3,
    const float* __restrict__ Wep1, const float* __restrict__ bep1,
    const float* __restrict__ Wep2, const float* __restrict__ bep2,
    const float* __restrict__ Wlp1, const float* __restrict__ blp1,
    const float* __restrict__ Wlp2, const float* __restrict__ blp2,
    float* __restrict__ out, float* __restrict__ efc, float* __restrict__ lfc,
    float* __restrict__ imgpart)
{
    int bid = blockIdx.x;
    int t   = threadIdx.x;

    if (bid < 1536) {
        // ---- conflict-masked max pool: out[m,c] = max_j mask[m,j]*x[j,c] ----
        __shared__ int   s_cnt;
        __shared__ int   s_idx[MM];
        __shared__ float s_val[MM];
        bool isLoop = bid >= MM;
        int  m      = bid & (MM - 1);
        const float* mask = isLoop ? lcm : ecm;
        const float* x    = isLoop ? loop_x : edge_x;
        float*       o    = isLoop ? lfc : efc;

        if (t == 0) s_cnt = 0;
        __syncthreads();
        int lane = t & 63;
        #pragma unroll
        for (int r = 0; r < 3; ++r) {
            int j = t + r * 256;
            float v = mask[m * MM + j];
            bool nz = (v != 0.0f);
            unsigned long long b = __ballot(nz);
            int prefix = __popcll(b & ((1ull << lane) - 1ull));
            int cntw   = __popcll(b);
            int base = 0;
            if (lane == 0 && cntw) base = atomicAdd(&s_cnt, cntw);
            base = __shfl(base, 0, 64);
            if (nz) { s_idx[base + prefix] = j; s_val[base + prefix] = v; }
        }
        __syncthreads();
        int cnt = s_cnt;
        float init = (cnt < MM) ? 0.0f : -INFINITY;  // zero entries contribute 0
        float a0 = init, a1 = init, a2 = init, a3 = init;
        int i = 0;
        for (; i + 4 <= cnt; i += 4) {
            a0 = fmaxf(a0, s_val[i + 0] * x[s_idx[i + 0] * CC + t]);
            a1 = fmaxf(a1, s_val[i + 1] * x[s_idx[i + 1] * CC + t]);
            a2 = fmaxf(a2, s_val[i + 2] * x[s_idx[i + 2] * CC + t]);
            a3 = fmaxf(a3, s_val[i + 3] * x[s_idx[i + 3] * CC + t]);
        }
        for (; i < cnt; ++i)
            a0 = fmaxf(a0, s_val[i] * x[s_idx[i] * CC + t]);
        o[m * CC + t] = fmaxf(fmaxf(a0, a1), fmaxf(a2, a3));

    } else if (bid < 1920) {
        // ---- pred0: one wave per row ----
        int wave = t >> 6, lane = t & 63;
        int row  = (bid - 1536) * 4 + wave;          // 0..1535
        const float *x, *W1, *b1, *W2;
        float b2v;
        if (row < MM) { x = edge_x + row * CC;        W1 = Wep1; b1 = bep1; W2 = Wep2; b2v = bep2[0]; }
        else          { x = loop_x + (row - MM) * CC; W1 = Wlp1; b1 = blp1; W2 = Wlp2; b2v = blp2[0]; }

        float a0 = 0.f, a1 = 0.f, a2 = 0.f, a3 = 0.f;
        for (int cc = 0; cc < CC; cc += 4) {
            float4 xv = *reinterpret_cast<const float4*>(x + cc);
            a0 = fmaf(xv.x, W1[(cc + 0) * 64 + lane], a0);
            a1 = fmaf(xv.y, W1[(cc + 1) * 64 + lane], a1);
            a2 = fmaf(xv.z, W1[(cc + 2) * 64 + lane], a2);
            a3 = fmaf(xv.w, W1[(cc + 3) * 64 + lane], a3);
        }
        float h = fmaxf(b1[lane] + ((a0 + a1) + (a2 + a3)), 0.0f);
        float p = h * W2[lane];
        #pragma unroll
        for (int off = 32; off; off >>= 1) p += __shfl_xor(p, off, 64);
        if (lane == 0) out[row] = sigmoidf_(p + b2v);

    } else {
        // ---- img bias partials ----
        int sub   = bid - 1920;       // 0..7
        int chunk = sub & 3;
        int head  = sub >> 2;
        const float* W = head ? Wl3 : We3;
        int k0 = chunk * 256;
        float s = 0.0f;
        #pragma unroll 4
        for (int k = 0; k < 256; ++k)
            s = fmaf(image_x[k0 + k], W[(768 + k0 + k) * CC + t], s);
        imgpart[head * 1024 + chunk * 256 + t] = s;
    }
}

// ===========================================================================
// Kernel B (grid 384 x 512): weighted broadcast sums, both directions.
//   blocks [0,192)  : efl[m,:]  (4 m-rows per block)
//   blocks [192,384): lfe[n,:]  (4 n-rows per block)
// Phase 1 computes the block's w-slice wv[768][4] ONCE into LDS (12KB) and
// the 4 normalization sums via wave shuffle-reduce. Phase 2 splits the
// 768-long summation across the two 256-thread halves, unrolled x4.
// ===========================================================================
__global__ __launch_bounds__(512) void k_bsum(
    const float* __restrict__ lem, const float* __restrict__ edge_x,
    const float* __restrict__ loop_x, const float* __restrict__ pred,
    float* __restrict__ efl, float* __restrict__ lfe)
{
    __shared__ float4 s_wv4[MM];     // 12KB: wv[s] = w[s][0..3]
    __shared__ float  s_pw[8 * 4];   // per-wave per-row partial sums
    __shared__ float  s_sum[4];
    float* s_wv = reinterpret_cast<float*>(s_wv4);

    int bid = blockIdx.x;
    int t   = threadIdx.x;
    const float* e0 = pred;
    const float* l0 = pred + MM;

    bool isE = bid < 192;
    int  r0  = (isE ? bid : bid - 192) * 4;
    const float* ownp = isE ? e0 : l0;
    const float* othp = isE ? l0 : e0;

    float own[4];
    #pragma unroll
    for (int i = 0; i < 4; ++i) own[i] = ownp[r0 + i];

    // phase 1: wv[s*4+i] = lem * |oth[s] - own[i]|; i == t&3 for all k
    int i_ = t & 3;
    float myown = own[0];
    if (i_ == 1) myown = own[1];
    else if (i_ == 2) myown = own[2];
    else if (i_ == 3) myown = own[3];
    float psum = 0.f;
    #pragma unroll
    for (int k = 0; k < 6; ++k) {
        int idx = t + k * 512;
        int s = idx >> 2;
        float lm = isE ? lem[s * MM + r0 + i_] : lem[(r0 + i_) * MM + s];
        float wv = lm * fabsf(othp[s] - myown);
        s_wv[idx] = wv;
        psum += wv;
    }
    // wave reduce psum across lanes with equal (lane&3)
    #pragma unroll
    for (int off = 4; off < 64; off <<= 1) psum += __shfl_xor(psum, off, 64);
    int wave = t >> 6, lane = t & 63;
    if (lane < 4) s_pw[wave * 4 + lane] = psum;
    __syncthreads();
    if (t < 4) {
        float s = 0.f;
        #pragma unroll
        for (int w = 0; w < 8; ++w) s += s_pw[w * 4 + t];
        s_sum[t] = fmaxf(s, EPSV);
    }

    // phase 2: half h accumulates s in [h*384, h*384+384), unroll x4
    const float* xsrc = isE ? loop_x : edge_x;
    int c = t & 255, h = t >> 8;
    float acc0 = 0.f, acc1 = 0.f, acc2 = 0.f, acc3 = 0.f;
    int s0 = h * 384;
    for (int s = s0; s < s0 + 384; s += 4) {
        float4 wa = s_wv4[s + 0];
        float4 wb = s_wv4[s + 1];
        float4 wc = s_wv4[s + 2];
        float4 wd = s_wv4[s + 3];
        float xa = xsrc[(s + 0) * CC + c];
        float xb = xsrc[(s + 1) * CC + c];
        float xc = xsrc[(s + 2) * CC + c];
        float xd = xsrc[(s + 3) * CC + c];
        acc0 = fmaf(wa.x, xa, acc0); acc1 = fmaf(wa.y, xa, acc1);
        acc2 = fmaf(wa.z, xa, acc2); acc3 = fmaf(wa.w, xa, acc3);
        acc0 = fmaf(wb.x, xb, acc0); acc1 = fmaf(wb.y, xb, acc1);
        acc2 = fmaf(wb.z, xb, acc2); acc3 = fmaf(wb.w, xb, acc3);
        acc0 = fmaf(wc.x, xc, acc0); acc1 = fmaf(wc.y, xc, acc1);
        acc2 = fmaf(wc.z, xc, acc2); acc3 = fmaf(wc.w, xc, acc3);
        acc0 = fmaf(wd.x, xd, acc0); acc1 = fmaf(wd.y, xd, acc1);
        acc2 = fmaf(wd.z, xd, acc2); acc3 = fmaf(wd.w, xd, acc3);
    }
    __syncthreads();                 // everyone done reading s_wv
    if (h == 1) {
        s_wv[0 * CC + c] = acc0; s_wv[1 * CC + c] = acc1;
        s_wv[2 * CC + c] = acc2; s_wv[3 * CC + c] = acc3;
    }
    __syncthreads();
    if (h == 0) {
        float* outp = isE ? efl : lfe;
        outp[(r0 + 0) * CC + c] = (acc0 + s_wv[0 * CC + c]) / s_sum[0];
        outp[(r0 + 1) * CC + c] = (acc1 + s_wv[1 * CC + c]) / s_sum[1];
        outp[(r0 + 2) * CC + c] = (acc2 + s_wv[2 * CC + c]) / s_sum[2];
        outp[(r0 + 3) * CC + c] = (acc3 + s_wv[3 * CC + c]) / s_sum[3];
    }
}

// ===========================================================================
// Kernel C (grid (192,2) x 512): x2 = relu(cat @ W + b) fused with pred1.
// 4 output rows per block; k split across thread-halves; act tile in LDS;
// pred head split across wave pairs. ex2/lx2 never hit global memory.
// ===========================================================================
__global__ __launch_bounds__(512) void k_cat(
    const float* __restrict__ edge_x, const float* __restrict__ loop_x,
    const float* __restrict__ efl, const float* __restrict__ lfe,
    const float* __restrict__ efc, const float* __restrict__ lfc,
    const float* __restrict__ We3, const float* __restrict__ be3,
    const float* __restrict__ Wl3, const float* __restrict__ bl3,
    const float* __restrict__ imgpart,
    const float* __restrict__ Wep1, const float* __restrict__ bep1,
    const float* __restrict__ Wep2, const float* __restrict__ bep2,
    const float* __restrict__ Wlp1, const float* __restrict__ blp1,
    const float* __restrict__ Wlp2, const float* __restrict__ blp2,
    float* __restrict__ out)
{
    __shared__ float s_part[4 * CC];   // 4KB: k-half partials
    __shared__ float s_act[4 * CC];    // 4KB: relu activations
    __shared__ float s_h[8 * 64];      // 2KB: pred-head partials

    int head = blockIdx.y;
    const float* W  = head ? Wl3 : We3;
    const float* b  = head ? bl3 : be3;
    const float* x0 = head ? loop_x : edge_x;
    const float* x1 = head ? lfe : efl;
    const float* x2 = head ? lfc : efc;
    const float* ip = imgpart + head * 1024;

    int m0 = blockIdx.x * 4;
    int t  = threadIdx.x;
    int c  = t & 255, h = t >> 8;

    float acc[4] = {0.f, 0.f, 0.f, 0.f};

    auto accum = [&](const float* src, int ks, int kw, int len) {
        for (int kk = 0; kk < len; kk += 4) {
            float4 xv[4];
            #pragma unroll
            for (int i = 0; i < 4; ++i)
                xv[i] = *reinterpret_cast<const float4*>(src + (m0 + i) * CC + ks + kk);
            #pragma unroll
            for (int j = 0; j < 4; ++j) {
                float wv = W[(kw + kk + j) * CC + c];
                #pragma unroll
                for (int i = 0; i < 4; ++i)
                    acc[i] = fmaf(reinterpret_cast<const float*>(&xv[i])[j], wv, acc[i]);
            }
        }
    };
    // concat rows: [0,256)=x, [256,512)=x_from_other, [512,768)=x_from_conflict
    if (h == 0) { accum(x0, 0, 0, 256);     accum(x1, 0, 256, 128); }
    else        { accum(x1, 128, 384, 128); accum(x2, 0, 512, 256); }

    if (h == 1) {
        #pragma unroll
        for (int i = 0; i < 4; ++i) s_part[i * CC + c] = acc[i];
    }
    __syncthreads();
    if (h == 0) {
        float bias = b[c] + ip[c] + ip[256 + c] + ip[512 + c] + ip[768 + c];
        #pragma unroll
        for (int i = 0; i < 4; ++i)
            s_act[i * CC + c] = fmaxf(bias + acc[i] + s_part[i * CC + c], 0.0f);
    }
    __syncthreads();

    // fused pred head: wave pair per row (wave = row*2 + khalf)
    int wave = t >> 6, lane = t & 63;
    int row = wave >> 1, khalf = wave & 1;
    const float* W1 = head ? Wlp1 : Wep1;
    const float* b1 = head ? blp1 : bep1;
    const float* W2 = head ? Wlp2 : Wep2;
    float b2v       = head ? blp2[0] : bep2[0];
    const float* xr = s_act + row * CC + khalf * 128;

    float a0 = 0.f, a1 = 0.f, a2 = 0.f, a3 = 0.f;
    for (int cc = 0; cc < 128; cc += 4) {
        float4 xv = *reinterpret_cast<const float4*>(xr + cc);
        int kb = khalf * 128 + cc;
        a0 = fmaf(xv.x, W1[(kb + 0) * 64 + lane], a0);
        a1 = fmaf(xv.y, W1[(kb + 1) * 64 + lane], a1);
        a2 = fmaf(xv.z, W1[(kb + 2) * 64 + lane], a2);
        a3 = fmaf(xv.w, W1[(kb + 3) * 64 + lane], a3);
    }
    s_h[wave * 64 + lane] = (a0 + a1) + (a2 + a3);
    __syncthreads();
    if (khalf == 0) {
        float hv = fmaxf(b1[lane] + s_h[wave * 64 + lane] + s_h[(wave + 1) * 64 + lane], 0.0f);
        float p = hv * W2[lane];
        #pragma unroll
        for (int off = 32; off; off >>= 1) p += __shfl_xor(p, off, 64);
        if (lane == 0) out[1536 + head * MM + m0 + row] = sigmoidf_(p + b2v);
    }
}

// ===========================================================================
extern "C" void kernel_launch(void* const* d_in, const int* in_sizes, int n_in,
                              void* d_out, int out_size, void* d_ws, size_t ws_size,
                              hipStream_t stream)
{
    const float* edge_x  = (const float*)d_in[0];
    const float* loop_x  = (const float*)d_in[1];
    const float* image_x = (const float*)d_in[2];
    const float* lem     = (const float*)d_in[3];
    const float* ecm     = (const float*)d_in[4];
    const float* lcm     = (const float*)d_in[5];
    // d_in[6..8] unused
    const float* We3  = (const float*)d_in[9];
    const float* be3  = (const float*)d_in[10];
    const float* Wl3  = (const float*)d_in[11];
    const float* bl3  = (const float*)d_in[12];
    const float* Wep1 = (const float*)d_in[13];
    const float* bep1 = (const float*)d_in[14];
    const float* Wep2 = (const float*)d_in[15];
    const float* bep2 = (const float*)d_in[16];
    const float* Wlp1 = (const float*)d_in[17];
    const float* blp1 = (const float*)d_in[18];
    const float* Wlp2 = (const float*)d_in[19];
    const float* blp2 = (const float*)d_in[20];

    float* out = (float*)d_out;          // [3072] = e0 | l0 | e1 | l1
    float* ws  = (float*)d_ws;

    // workspace (floats): imgpart 2048 | efl | lfe | efc | lfc  (~3.15 MB)
    float* imgpart = ws;
    float* efl     = ws + 2048;
    float* lfe     = efl + MM * CC;
    float* efc     = lfe + MM * CC;
    float* lfc     = efc + MM * CC;

    // A: conflict pools + pred0 + img-bias (independent)
    k_prep<<<1928, 256, 0, stream>>>(edge_x, loop_x, image_x, ecm, lcm,
                                     We3, Wl3,
                                     Wep1, bep1, Wep2, bep2,
                                     Wlp1, blp1, Wlp2, blp2,
                                     out, efc, lfc, imgpart);

    // B: both weighted broadcast sums (reads e0/l0 from out)
    k_bsum<<<384, 512, 0, stream>>>(lem, edge_x, loop_x, out, efl, lfe);

    // C: concat-GEMM + relu + fused pred1
    k_cat<<<dim3(192, 2), 512, 0, stream>>>(edge_x, loop_x, efl, lfe, efc, lfc,
                                            We3, be3, Wl3, bl3, imgpart,
                                            Wep1, bep1, Wep2, bep2,
                                            Wlp1, blp1, Wlp2, blp2, out);
}